// Round 10
// baseline (260.029 us; speedup 1.0000x reference)
//
#include <hip/hip_runtime.h>
#include <hip/hip_cooperative_groups.h>
#include <stdint.h>
#include <stddef.h>

namespace cg = cooperative_groups;

#define B_ 8
#define L_ 2048
#define D_ 256
#define KRANGE 512
#define KTILE 32
#define NITER 16

typedef __bf16 bf16x8 __attribute__((ext_vector_type(8)));
typedef float floatx4 __attribute__((ext_vector_type(4)));
typedef float floatx16 __attribute__((ext_vector_type(16)));
typedef _Float16 half8_t __attribute__((ext_vector_type(8)));

__device__ __forceinline__ short f2bf(float f) {   // round-half-up (cheap)
    union { float f; uint32_t u; } v; v.f = f;
    return (short)((v.u + 0x8000u) >> 16);
}

__device__ __forceinline__ uint32_t pack2bf(float a, float b) {
    union { float f; uint32_t u; } x, y; x.f = a; y.f = b;
    return ((x.u + 0x8000u) >> 16) | ((y.u + 0x8000u) & 0xFFFF0000u);
}

__device__ __forceinline__ uint32_t cvtpk_bf16(float lo, float hi2) {
    uint32_t w;
    asm("v_cvt_pk_bf16_f32 %0, %1, %2" : "=v"(w) : "v"(lo), "v"(hi2));
    return w;
}

// swap(a[l+32], b[l]) for l<32: a's upper lanes <-> b's lower lanes
__device__ __forceinline__ void pl32swap(uint32_t &a, uint32_t &b) {
    asm("v_permlane32_swap_b32 %0, %1" : "+v"(a), "+v"(b));
}

__device__ __forceinline__ void async16(const void* g, void* l) {
    __builtin_amdgcn_global_load_lds(
        (__attribute__((address_space(1))) void*)g,
        (__attribute__((address_space(3))) void*)l,
        16, 0, 0);
}

// ---------------------------------------------------------------------------
// Single cooperative kernel: prep (vtrans + q/k proj) -> grid sync ->
// flash (R9-proven 3-deep counted-vmcnt pipeline) -> grid sync -> norm.
// 256 blocks x 512 threads = 1 block/CU (co-resident by construction).
// Removes 3 kernel-launch gaps (~115us non-flash block in R9 vs ~45us of
// accountable work).
// ---------------------------------------------------------------------------
extern "C" __global__ __launch_bounds__(512, 2) void fused_kernel(
    const float* __restrict__ query, const float* __restrict__ key,
    const float* __restrict__ value, const int* __restrict__ mask,
    const float* __restrict__ Wq_w, const float* __restrict__ Wq_b,
    const float* __restrict__ Wk_w, const float* __restrict__ Wk_b,
    short* __restrict__ qb, short* __restrict__ kb, short* __restrict__ vt,
    float* __restrict__ out, _Float16* __restrict__ part,
    float* __restrict__ lpart)
{
    __shared__ char smem[98304];   // 96 KB arena shared by all phases

    cg::grid_group grid = cg::this_grid();

    const int tid = threadIdx.x;
    const int bid = blockIdx.x + blockIdx.y * 8 + blockIdx.z * 64;  // 0..255

    // =====================================================================
    // Phase A1: V transpose — 2 tiles per block (thread halves, 256 each)
    // =====================================================================
    {
        uint32_t* T = (uint32_t*)smem + (tid >> 8) * (256 * 20);  // 20KB/half
        const int t2 = tid & 255;
        const int vb = bid * 2 + (tid >> 8);        // 0..511
        const int b  = vb >> 6;
        const int l0 = (vb & 63) * 32;
        const int r2 = t2 >> 4;
        const int dg = t2 & 15;
        const int lp = r2 ^ ((dg & 3) << 2);
#pragma unroll
        for (int p = 0; p < 4; p++) {
            int d0 = (dg + p * 16) * 4;
            const float* src = value + ((size_t)b * L_ + l0 + r2 * 2) * D_ + d0;
            float4 e0 = *(const float4*)src;
            float4 e1 = *(const float4*)(src + D_);
            T[(d0 + 0) * 20 + lp] = pack2bf(e0.x, e1.x);
            T[(d0 + 1) * 20 + lp] = pack2bf(e0.y, e1.y);
            T[(d0 + 2) * 20 + lp] = pack2bf(e0.z, e1.z);
            T[(d0 + 3) * 20 + lp] = pack2bf(e0.w, e1.w);
        }
        __syncthreads();
#pragma unroll
        for (int p = 0; p < 4; p++) {
            int d = (t2 >> 2) + p * 64;
            int c = t2 & 3;
            int cp = c ^ ((d >> 2) & 3);
            uint4 u = *(const uint4*)&T[d * 20 + cp * 4];
            *(uint4*)(vt + ((size_t)b * D_ + d) * L_ + l0 + c * 8) = u;
        }
    }
    __syncthreads();

    // =====================================================================
    // Phase A2: q/k projection — 128-row slab per block, 8 waves
    // =====================================================================
    {
        const int py = bid >> 7;           // 0=q, 1=k
        const int px = bid & 127;
        const float* X    = py ? key  : query;
        const float* W    = py ? Wk_w : Wq_w;
        const float* bias = py ? Wk_b : Wq_b;
        short* Out        = py ? kb   : qb;

        uint32_t* As = (uint32_t*)smem;          // 2 x 128*20 u32 (20 KB)
        uint32_t* Ws = (uint32_t*)smem + 2 * 2560;  // 2 x 256*20 u32 (40 KB)

        const int wid8 = tid >> 6;   // 0..7
        const int lane = tid & 63;
        const int m16  = lane & 15;
        const int quad = lane >> 4;
        const int row0 = px * 128;
        const int ar = tid >> 2, cg2 = tid & 3;

        floatx4 acc[16];
        const floatx4 z4 = {0.f, 0.f, 0.f, 0.f};
#pragma unroll
        for (int i = 0; i < 16; i++) acc[i] = z4;

        // prologue: load + pack kc=0 into buf 0
        {
            const float* srcA = X + (size_t)(row0 + ar) * D_ + cg2 * 8;
            float4 a = *(const float4*)srcA, b2 = *(const float4*)(srcA + 4);
            uint4 u; u.x = pack2bf(a.x, a.y); u.y = pack2bf(a.z, a.w);
            u.z = pack2bf(b2.x, b2.y); u.w = pack2bf(b2.z, b2.w);
            *(uint4*)&As[ar * 20 + cg2 * 4] = u;
#pragma unroll
            for (int p = 0; p < 2; p++) {
                const float* srcW = W + (size_t)(p * 128 + ar) * D_ + cg2 * 8;
                float4 wa = *(const float4*)srcW, wb = *(const float4*)(srcW + 4);
                uint4 w; w.x = pack2bf(wa.x, wa.y); w.y = pack2bf(wa.z, wa.w);
                w.z = pack2bf(wb.x, wb.y); w.w = pack2bf(wb.z, wb.w);
                *(uint4*)&Ws[(p * 128 + ar) * 20 + cg2 * 4] = w;
            }
        }
        __syncthreads();

        for (int kc = 0; kc < 8; kc++) {
            const int buf = kc & 1;
            float4 na, nb, nwa[2], nwb[2];
            if (kc < 7) {
                const int k1 = (kc + 1) * 32;
                const float* srcA = X + (size_t)(row0 + ar) * D_ + k1 + cg2 * 8;
                na = *(const float4*)srcA; nb = *(const float4*)(srcA + 4);
#pragma unroll
                for (int p = 0; p < 2; p++) {
                    const float* srcW = W + (size_t)(p * 128 + ar) * D_ + k1 + cg2 * 8;
                    nwa[p] = *(const float4*)srcW; nwb[p] = *(const float4*)(srcW + 4);
                }
            }
            bf16x8 af = *(const bf16x8*)&As[buf * 2560 + (wid8 * 16 + m16) * 20 + quad * 4];
#pragma unroll
            for (int n = 0; n < 16; n++) {
                bf16x8 bfr = *(const bf16x8*)&Ws[buf * 5120 + (n * 16 + m16) * 20 + quad * 4];
                acc[n] = __builtin_amdgcn_mfma_f32_16x16x32_bf16(af, bfr, acc[n], 0, 0, 0);
            }
            if (kc < 7) {
                uint4 u; u.x = pack2bf(na.x, na.y); u.y = pack2bf(na.z, na.w);
                u.z = pack2bf(nb.x, nb.y); u.w = pack2bf(nb.z, nb.w);
                *(uint4*)&As[(buf ^ 1) * 2560 + ar * 20 + cg2 * 4] = u;
#pragma unroll
                for (int p = 0; p < 2; p++) {
                    uint4 w; w.x = pack2bf(nwa[p].x, nwa[p].y); w.y = pack2bf(nwa[p].z, nwa[p].w);
                    w.z = pack2bf(nwb[p].x, nwb[p].y); w.w = pack2bf(nwb[p].z, nwb[p].w);
                    *(uint4*)&Ws[(buf ^ 1) * 5120 + (p * 128 + ar) * 20 + cg2 * 4] = w;
                }
            }
            __syncthreads();
        }
#pragma unroll
        for (int n = 0; n < 16; n++) {
            const int col = n * 16 + m16;
            const float bv = bias[col];
#pragma unroll
            for (int r = 0; r < 4; r++) {
                const int row = row0 + wid8 * 16 + quad * 4 + r;
                Out[(size_t)row * D_ + col] = f2bf(acc[n][r] + bv);
            }
        }
    }

    grid.sync();   // qb, kb, vt complete and visible device-wide

    // =====================================================================
    // Phase B: flash attention (R9 core, verbatim; smem re-based)
    // =====================================================================
    {
        short* KsB = (short*)smem;                 // 3 x 16 KB
        short* VsB = KsB + 3 * KTILE * 256;        // 3 x 16 KB

        const int wid  = tid >> 6;          // 0..7
        const int lane = tid & 63;
        const int l31  = lane & 31;
        const int hi   = lane >> 5;
        const int b  = blockIdx.x;
        const int yb = blockIdx.y;
        const int q0 = yb * 256;
        const int z  = blockIdx.z;

        const char* kgb = (const char*)(kb + ((size_t)b * L_ + z * KRANGE) * D_);
        const char* vgb = (const char*)(vt + (size_t)b * D_ * L_ + z * KRANGE);
        const int*  mg  = mask + b * L_ + z * KRANGE;

        // Q as MFMA B-operand: lane holds Q[q = l31][d = dt*16 + hi*8 + 0..7]
        bf16x8 qf[16];
        {
            const short* qrow = qb + ((size_t)b * L_ + q0 + wid * 32 + l31) * D_ + hi * 8;
#pragma unroll
            for (int dt = 0; dt < 16; dt++)
                qf[dt] = *(const bf16x8*)(qrow + dt * 16);
        }

        uint32_t mbits = 0;
#pragma unroll
        for (int t = 0; t < NITER; t++)
            mbits |= (mg[t * KTILE + l31] != 0 ? 1u : 0u) << t;

        floatx16 o[8];
#pragma unroll
        for (int n = 0; n < 8; n++)
#pragma unroll
            for (int r = 0; r < 16; r++) o[n][r] = 0.f;
        float rsum = 0.f;

        const int KBb = l31 * 512 + ((((l31 & 7) ^ ((l31 >> 3) & 3)) ^ hi) << 4);
        const int VBb = l31 * 64 + (((((l31 >> 1) & 3) ^ ((l31 >> 3) & 1)) ^ hi) << 4);

        int koff[2], voff[2];
#pragma unroll
        for (int c = 0; c < 2; c++) {
            int row = wid * 4 + c * 2 + hi;
            int gk = l31 ^ (row & 7) ^ ((row >> 3) & 3);
            koff[c] = row * 512 + gk * 16;
            int d = (wid * 2 + c) * 16 + (lane >> 2);
            int gv = (lane & 3) ^ ((lane >> 3) & 3) ^ ((lane >> 5) & 1);
            voff[c] = d * (L_ * 2) + gv * 16;
        }

        // prologue: K(0)->Ks0, K(1)->Ks1; V(0)->Vs2 (dummy PV target) + Vs0
#pragma unroll
        for (int c = 0; c < 2; c++) {
            async16(kgb + koff[c], (char*)KsB + (wid * 2 + c) * 1024);
            async16(vgb + voff[c], (char*)(VsB + 2 * 256 * KTILE) + (wid * 2 + c) * 1024);
            async16(kgb + (KTILE * D_ * 2) + koff[c], (char*)(KsB + KTILE * 256) + (wid * 2 + c) * 1024);
            async16(vgb + voff[c], (char*)VsB + (wid * 2 + c) * 1024);
        }
        __builtin_amdgcn_s_waitcnt(0x0F70);  // vmcnt(0) once, in prologue
        __syncthreads();

        const float C2 = 0.09016844f;        // log2(e)/16
        bf16x8 pfA, pfB;
        {
            union { uint32_t u[4]; bf16x8 v; } zz;
            zz.u[0] = 0; zz.u[1] = 0; zz.u[2] = 0; zz.u[3] = 0;
            pfA = zz.v; pfB = zz.v;
        }

        short* kCur = KsB; short* kNxt = KsB + KTILE * 256; short* kDst = KsB + 2 * KTILE * 256;
        short* vP = VsB + 2 * 256 * KTILE; short* vQ = VsB; short* vR = VsB + 256 * KTILE;

        for (int t = 0; t < NITER; t++) {
            {
                const char* kp = kgb + (size_t)((t + 2) & 15) * (KTILE * D_ * 2);
                const char* vp = vgb + (size_t)((t + 1) & 15) * (KTILE * 2);
#pragma unroll
                for (int c = 0; c < 2; c++) {
                    async16(kp + koff[c], (char*)kDst + (wid * 2 + c) * 1024);
                    async16(vp + voff[c], (char*)vR + (wid * 2 + c) * 1024);
                }
            }

            const char* kl = (const char*)kCur;
            floatx16 s0, s1;
#pragma unroll
            for (int r = 0; r < 16; r++) { s0[r] = 0.f; s1[r] = 0.f; }
            __builtin_amdgcn_s_setprio(1);
#pragma unroll
            for (int dt = 0; dt < 16; dt += 2) {
                bf16x8 kf0 = *(const bf16x8*)(kl + (KBb ^ (dt << 5)));
                bf16x8 kf1 = *(const bf16x8*)(kl + (KBb ^ ((dt + 1) << 5)));
                s0 = __builtin_amdgcn_mfma_f32_32x32x16_bf16(kf0, qf[dt], s0, 0, 0, 0);
                s1 = __builtin_amdgcn_mfma_f32_32x32x16_bf16(kf1, qf[dt + 1], s1, 0, 0, 0);
            }

            const char* vl = (const char*)vP;
#pragma unroll
            for (int n = 0; n < 8; n++) {
                bf16x8 vf0 = *(const bf16x8*)(vl + (VBb ^ (n << 11)));
                bf16x8 vf1 = *(const bf16x8*)(vl + (VBb ^ ((n << 11) | 32)));
                o[n] = __builtin_amdgcn_mfma_f32_32x32x16_bf16(pfA, vf0, o[n], 0, 0, 0);
                o[n] = __builtin_amdgcn_mfma_f32_32x32x16_bf16(pfB, vf1, o[n], 0, 0, 0);
            }
            __builtin_amdgcn_s_setprio(0);

            uint32_t mb = (uint32_t)__ballot((mbits >> t) & 1) >> (hi * 4);
            uint32_t w[8];
#pragma unroll
            for (int i = 0; i < 8; i++) {
                const int r0 = 2 * i, r1 = 2 * i + 1;
                const int k0 = (r0 & 3) + 8 * (r0 >> 2);
                float sv0 = s0[r0] + s1[r0];
                float sv1 = s0[r1] + s1[r1];
                float e0 = ((mb >> k0) & 1) ? exp2f(sv0 * C2) : 0.f;
                float e1 = ((mb >> (k0 + 1)) & 1) ? exp2f(sv1 * C2) : 0.f;
                rsum += e0 + e1;
                w[i] = cvtpk_bf16(e0, e1);
            }
            pl32swap(w[0], w[2]); pl32swap(w[1], w[3]);
            pl32swap(w[4], w[6]); pl32swap(w[5], w[7]);
            {
                union { uint32_t u[4]; bf16x8 v; } ua, ub;
                ua.u[0] = w[0]; ua.u[1] = w[1]; ua.u[2] = w[2]; ua.u[3] = w[3];
                ub.u[0] = w[4]; ub.u[1] = w[5]; ub.u[2] = w[6]; ub.u[3] = w[7];
                pfA = ua.v; pfB = ub.v;
            }

            asm volatile("s_waitcnt vmcnt(4)" ::: "memory");
            __builtin_amdgcn_s_barrier();
            asm volatile("" ::: "memory");

            short* tk = kCur; kCur = kNxt; kNxt = kDst; kDst = tk;
            short* tv = vP;   vP = vQ;     vQ = vR;     vR = tv;
        }

        // final PV(NITER-1)
        {
            const char* vl = (const char*)vP;
            __builtin_amdgcn_s_setprio(1);
#pragma unroll
            for (int n = 0; n < 8; n++) {
                bf16x8 vf0 = *(const bf16x8*)(vl + (VBb ^ (n << 11)));
                bf16x8 vf1 = *(const bf16x8*)(vl + (VBb ^ ((n << 11) | 32)));
                o[n] = __builtin_amdgcn_mfma_f32_32x32x16_bf16(pfA, vf0, o[n], 0, 0, 0);
                o[n] = __builtin_amdgcn_mfma_f32_32x32x16_bf16(pfB, vf1, o[n], 0, 0, 0);
            }
            __builtin_amdgcn_s_setprio(0);
        }

        rsum += __shfl_xor(rsum, 32);

        const size_t BLD = (size_t)B_ * L_ * D_;
        const size_t rowbase = (size_t)b * L_ + q0 + wid * 32;
        if (z == 0) {
            float* po = out + rowbase * D_;
#pragma unroll
            for (int n = 0; n < 8; n++)
#pragma unroll
                for (int r = 0; r < 16; r++) {
                    int q = (r & 3) + 8 * (r >> 2) + 4 * hi;
                    po[(size_t)q * D_ + n * 32 + l31] = o[n][r];
                }
        } else {
            _Float16* pp = part + (size_t)(z - 1) * BLD;
#pragma unroll
            for (int n = 0; n < 8; n++)
#pragma unroll
                for (int h2 = 0; h2 < 2; h2++) {
                    half8_t hv;
#pragma unroll
                    for (int i = 0; i < 8; i++) hv[i] = (_Float16)o[n][h2 * 8 + i];
                    size_t cidx = ((((size_t)((b * 8 + yb) * 8 + wid)) * 8 + n) * 2 + h2) * 64 + lane;
                    *(half8_t*)(pp + cidx * 8) = hv;
                }
        }
        if (lane < 32) {
            lpart[(size_t)z * (B_ * L_) + rowbase + lane] = rsum;
        }
    }

    grid.sync();   // out(z0), part, lpart complete and visible device-wide

    // =====================================================================
    // Phase C: normalize — 4 chunks per thread across all blocks
    // =====================================================================
    {
        const size_t BLD = (size_t)B_ * L_ * D_;
        const int BL = B_ * L_;
        const int base = bid * 512 + tid;   // 0..131071
#pragma unroll
        for (int k = 0; k < 4; k++) {
            const int gid  = base + k * 131072;   // 0..524287
            const int lane = gid & 63;
            const int h2   = (gid >> 6) & 1;
            const int n    = (gid >> 7) & 7;
            const int wv   = (gid >> 10) & 7;
            const int yb   = (gid >> 13) & 7;
            const int b    = gid >> 16;
            const int l31  = lane & 31, hi = lane >> 5;
            const int d    = n * 32 + l31;
            const int rowbase = b * L_ + yb * 256 + wv * 32;

            float acc[8];
#pragma unroll
            for (int i = 0; i < 8; i++) acc[i] = 0.f;
#pragma unroll
            for (int zz = 0; zz < 3; zz++) {
                half8_t hv = *(const half8_t*)(part + zz * BLD + (size_t)gid * 8);
#pragma unroll
                for (int i = 0; i < 8; i++) acc[i] += (float)hv[i];
            }
#pragma unroll
            for (int i = 0; i < 8; i++) {
                const int r = h2 * 8 + i;
                const int q = (r & 3) + 8 * (r >> 2) + 4 * hi;
                const int row = rowbase + q;
                float l = lpart[row] + lpart[BL + row] + lpart[2 * BL + row] + lpart[3 * BL + row];
                const size_t off = (size_t)row * D_ + d;
                out[off] = (out[off] + acc[i]) / l;
            }
        }
    }
}

extern "C" void kernel_launch(void* const* d_in, const int* in_sizes, int n_in,
                              void* d_out, int out_size, void* d_ws, size_t ws_size,
                              hipStream_t stream) {
    const float* query = (const float*)d_in[0];
    const float* key   = (const float*)d_in[1];
    const float* value = (const float*)d_in[2];
    const int*   mask  = (const int*)d_in[3];
    const float* Wq_w  = (const float*)d_in[4];
    const float* Wq_b  = (const float*)d_in[5];
    const float* Wk_w  = (const float*)d_in[6];
    const float* Wk_b  = (const float*)d_in[7];
    float* out = (float*)d_out;

    const size_t BLD = (size_t)B_ * L_ * D_;
    short* qb = (short*)d_ws;
    short* kb = qb + BLD;
    short* vt = kb + BLD;
    _Float16* part = (_Float16*)(vt + BLD);
    float* lpart = (float*)(part + 3 * BLD);

    void* args[] = {
        (void*)&query, (void*)&key, (void*)&value, (void*)&mask,
        (void*)&Wq_w, (void*)&Wq_b, (void*)&Wk_w, (void*)&Wk_b,
        (void*)&qb, (void*)&kb, (void*)&vt,
        (void*)&out, (void*)&part, (void*)&lpart
    };
    hipLaunchCooperativeKernel((const void*)fused_kernel, dim3(8, 8, 4), dim3(512),
                               args, 0, stream);
}

// Round 12
// 165.063 us; speedup vs baseline: 1.5753x; 1.5753x over previous
//
#include <hip/hip_runtime.h>
#include <stdint.h>
#include <stddef.h>

#define B_ 8
#define L_ 2048
#define D_ 256
#define KRANGE 512
#define KTILE 32
#define NITER 16

typedef __bf16 bf16x8 __attribute__((ext_vector_type(8)));
typedef float floatx4 __attribute__((ext_vector_type(4)));
typedef float floatx16 __attribute__((ext_vector_type(16)));
typedef _Float16 half8_t __attribute__((ext_vector_type(8)));

__device__ __forceinline__ short f2bf(float f) {   // round-half-up (cheap)
    union { float f; uint32_t u; } v; v.f = f;
    return (short)((v.u + 0x8000u) >> 16);
}

__device__ __forceinline__ uint32_t pack2bf(float a, float b) {
    union { float f; uint32_t u; } x, y; x.f = a; y.f = b;
    return ((x.u + 0x8000u) >> 16) | ((y.u + 0x8000u) & 0xFFFF0000u);
}

__device__ __forceinline__ uint32_t cvtpk_bf16(float lo, float hi2) {
    uint32_t w;
    asm("v_cvt_pk_bf16_f32 %0, %1, %2" : "=v"(w) : "v"(lo), "v"(hi2));
    return w;
}

// swap(a[l+32], b[l]) for l<32: a's upper lanes <-> b's lower lanes
__device__ __forceinline__ void pl32swap(uint32_t &a, uint32_t &b) {
    asm("v_permlane32_swap_b32 %0, %1" : "+v"(a), "+v"(b));
}

__device__ __forceinline__ void async16(const void* g, void* l) {
    __builtin_amdgcn_global_load_lds(
        (__attribute__((address_space(1))) void*)g,
        (__attribute__((address_space(3))) void*)l,
        16, 0, 0);
}

// ---------------------------------------------------------------------------
// Merged prep: every block does ONE vtrans tile (sequentially) then ONE
// proj slab. No divergent block paths (R4's failure mode) — vtrans section
// runs at proj's occupancy (12 waves/CU vs 8 standalone). 512 blocks.
//   vtrans: Vt[b][d][l] = bf16(V[b][l][d]);  tile = bid -> (b, l0)
//   proj:   Out = bf16(X @ W^T + bias);      slab = bid -> (q/k, 64 rows)
// ---------------------------------------------------------------------------
__global__ __launch_bounds__(256, 3) void prep_kernel(
    const float* __restrict__ Xq, const float* __restrict__ Xk,
    const float* __restrict__ Wq, const float* __restrict__ Wk,
    const float* __restrict__ bq, const float* __restrict__ bk,
    const float* __restrict__ V,
    short* __restrict__ Oq, short* __restrict__ Ok, short* __restrict__ Vt)
{
    __shared__ uint32_t shm[12800];   // 51.2 KB arena (vtrans T / proj As+Ws)
    const int tid = threadIdx.x;
    const int bid = blockIdx.x;       // 0..511

    // ---------------- phase 1: vtrans tile ----------------
    {
        uint32_t* T = shm;            // 256*20 u32 = 20 KB
        const int b  = bid >> 6;
        const int l0 = (bid & 63) * 32;
        const int r2 = tid >> 4;
        const int dg = tid & 15;
        const int lp = r2 ^ ((dg & 3) << 2);
#pragma unroll
        for (int p = 0; p < 4; p++) {
            int d0 = (dg + p * 16) * 4;
            const float* src = V + ((size_t)b * L_ + l0 + r2 * 2) * D_ + d0;
            float4 e0 = *(const float4*)src;
            float4 e1 = *(const float4*)(src + D_);
            T[(d0 + 0) * 20 + lp] = pack2bf(e0.x, e1.x);
            T[(d0 + 1) * 20 + lp] = pack2bf(e0.y, e1.y);
            T[(d0 + 2) * 20 + lp] = pack2bf(e0.z, e1.z);
            T[(d0 + 3) * 20 + lp] = pack2bf(e0.w, e1.w);
        }
        __syncthreads();
#pragma unroll
        for (int p = 0; p < 4; p++) {
            int d = (tid >> 2) + p * 64;
            int c = tid & 3;
            int cp = c ^ ((d >> 2) & 3);
            uint4 u = *(const uint4*)&T[d * 20 + cp * 4];
            *(uint4*)(Vt + ((size_t)b * D_ + d) * L_ + l0 + c * 8) = u;
        }
    }
    __syncthreads();   // T reads done before proj overwrites the arena

    // ---------------- phase 2: proj slab ----------------
    {
        const int py = bid >> 8;          // 0=q, 1=k
        const int px = bid & 255;
        const float* X    = py ? Xk : Xq;
        const float* W    = py ? Wk : Wq;
        const float* bias = py ? bk : bq;
        short* Out        = py ? Ok : Oq;

        uint32_t* As = shm;               // 2 x 64*20  u32 (10.24 KB)
        uint32_t* Ws = shm + 2 * 1280;    // 2 x 256*20 u32 (40.96 KB)

        const int wid  = tid >> 6;
        const int lane = tid & 63;
        const int m16  = lane & 15;
        const int quad = lane >> 4;
        const int row0 = px * 64;
        const int ar = tid >> 2, cg = tid & 3;

        floatx4 acc[16];
        const floatx4 z4 = {0.f, 0.f, 0.f, 0.f};
#pragma unroll
        for (int i = 0; i < 16; i++) acc[i] = z4;

        // prologue: load + pack kc=0 into buf 0
        {
            const float* srcA = X + (size_t)(row0 + ar) * D_ + cg * 8;
            float4 a = *(const float4*)srcA, b2 = *(const float4*)(srcA + 4);
            uint4 u; u.x = pack2bf(a.x, a.y); u.y = pack2bf(a.z, a.w);
            u.z = pack2bf(b2.x, b2.y); u.w = pack2bf(b2.z, b2.w);
            *(uint4*)&As[ar * 20 + cg * 4] = u;
#pragma unroll
            for (int p = 0; p < 4; p++) {
                const float* srcW = W + (size_t)(p * 64 + ar) * D_ + cg * 8;
                float4 wa = *(const float4*)srcW, wb = *(const float4*)(srcW + 4);
                uint4 w; w.x = pack2bf(wa.x, wa.y); w.y = pack2bf(wa.z, wa.w);
                w.z = pack2bf(wb.x, wb.y); w.w = pack2bf(wb.z, wb.w);
                *(uint4*)&Ws[(p * 64 + ar) * 20 + cg * 4] = w;
            }
        }
        __syncthreads();

        for (int kc = 0; kc < 8; kc++) {
            const int buf = kc & 1;
            float4 na, nb, nwa[4], nwb[4];
            if (kc < 7) {
                const int k1 = (kc + 1) * 32;
                const float* srcA = X + (size_t)(row0 + ar) * D_ + k1 + cg * 8;
                na = *(const float4*)srcA; nb = *(const float4*)(srcA + 4);
#pragma unroll
                for (int p = 0; p < 4; p++) {
                    const float* srcW = W + (size_t)(p * 64 + ar) * D_ + k1 + cg * 8;
                    nwa[p] = *(const float4*)srcW; nwb[p] = *(const float4*)(srcW + 4);
                }
            }
            bf16x8 af = *(const bf16x8*)&As[buf * 1280 + (wid * 16 + m16) * 20 + quad * 4];
#pragma unroll
            for (int n = 0; n < 16; n++) {
                bf16x8 bfr = *(const bf16x8*)&Ws[buf * 5120 + (n * 16 + m16) * 20 + quad * 4];
                acc[n] = __builtin_amdgcn_mfma_f32_16x16x32_bf16(af, bfr, acc[n], 0, 0, 0);
            }
            if (kc < 7) {
                uint4 u; u.x = pack2bf(na.x, na.y); u.y = pack2bf(na.z, na.w);
                u.z = pack2bf(nb.x, nb.y); u.w = pack2bf(nb.z, nb.w);
                *(uint4*)&As[(buf ^ 1) * 1280 + ar * 20 + cg * 4] = u;
#pragma unroll
                for (int p = 0; p < 4; p++) {
                    uint4 w; w.x = pack2bf(nwa[p].x, nwa[p].y); w.y = pack2bf(nwa[p].z, nwa[p].w);
                    w.z = pack2bf(nwb[p].x, nwb[p].y); w.w = pack2bf(nwb[p].z, nwb[p].w);
                    *(uint4*)&Ws[(buf ^ 1) * 5120 + (p * 64 + ar) * 20 + cg * 4] = w;
                }
            }
            __syncthreads();
        }
#pragma unroll
        for (int n = 0; n < 16; n++) {
            const int col = n * 16 + m16;
            const float bv = bias[col];
#pragma unroll
            for (int r = 0; r < 4; r++) {
                const int row = row0 + wid * 16 + quad * 4 + r;
                Out[(size_t)row * D_ + col] = f2bf(acc[n][r] + bv);
            }
        }
    }
}

// ---------------------------------------------------------------------------
// Flash attention (R9-proven, byte-identical): static softmax, ksplit=4,
// 32x32x16 MFMA, swapped QK^T, in-register P via cvt_pk + permlane32_swap,
// 3-deep K/V LDS buffers, raw s_barrier + counted vmcnt(4).
// 8 waves / 256 q-rows / block, grid 8x8x4 = 256 blocks = 1/CU.
// ---------------------------------------------------------------------------
__global__ __launch_bounds__(512, 2) void flash_kernel(
    const short* __restrict__ Qb, const short* __restrict__ Kb,
    const short* __restrict__ Vt, const int* __restrict__ mask,
    float* __restrict__ Out, _Float16* __restrict__ Part,
    float* __restrict__ Lpart)
{
    __shared__ short Ks[3][KTILE * 256];   // 3 x 16 KB
    __shared__ short Vs[3][256 * KTILE];   // 3 x 16 KB

    const int tid  = threadIdx.x;
    const int wid  = tid >> 6;          // 0..7
    const int lane = tid & 63;
    const int l31  = lane & 31;
    const int hi   = lane >> 5;
    const int b  = blockIdx.x;
    const int yb = blockIdx.y;
    const int q0 = yb * 256;
    const int z  = blockIdx.z;

    const char* kgb = (const char*)(Kb + ((size_t)b * L_ + z * KRANGE) * D_);
    const char* vgb = (const char*)(Vt + (size_t)b * D_ * L_ + z * KRANGE);
    const int*  mg  = mask + b * L_ + z * KRANGE;

    // Q as MFMA B-operand: lane holds Q[q = l31][d = dt*16 + hi*8 + 0..7]
    bf16x8 qf[16];
    {
        const short* qrow = Qb + ((size_t)b * L_ + q0 + wid * 32 + l31) * D_ + hi * 8;
#pragma unroll
        for (int dt = 0; dt < 16; dt++)
            qf[dt] = *(const bf16x8*)(qrow + dt * 16);
    }

    // preload mask bits: bit t = mask[z*KRANGE + t*32 + l31]
    uint32_t mbits = 0;
#pragma unroll
    for (int t = 0; t < NITER; t++)
        mbits |= (mg[t * KTILE + l31] != 0 ? 1u : 0u) << t;

    floatx16 o[8];
#pragma unroll
    for (int n = 0; n < 8; n++)
#pragma unroll
        for (int r = 0; r < 16; r++) o[n][r] = 0.f;
    float rsum = 0.f;

    const int KBb = l31 * 512 + ((((l31 & 7) ^ ((l31 >> 3) & 3)) ^ hi) << 4);
    const int VBb = l31 * 64 + (((((l31 >> 1) & 3) ^ ((l31 >> 3) & 1)) ^ hi) << 4);

    int koff[2], voff[2];
#pragma unroll
    for (int c = 0; c < 2; c++) {
        int row = wid * 4 + c * 2 + hi;
        int gk = l31 ^ (row & 7) ^ ((row >> 3) & 3);
        koff[c] = row * 512 + gk * 16;
        int d = (wid * 2 + c) * 16 + (lane >> 2);
        int gv = (lane & 3) ^ ((lane >> 3) & 3) ^ ((lane >> 5) & 1);
        voff[c] = d * (L_ * 2) + gv * 16;
    }

    // prologue: K(0)->Ks[0], K(1)->Ks[1]; V(0)->Vs[2] (dummy target of the
    // t=0 zero-P PV: 0*finite, never 0*garbage) and V(0)->Vs[0].
#pragma unroll
    for (int c = 0; c < 2; c++) {
        async16(kgb + koff[c], (char*)&Ks[0][0] + (wid * 2 + c) * 1024);
        async16(vgb + voff[c], (char*)&Vs[2][0] + (wid * 2 + c) * 1024);
        async16(kgb + (KTILE * D_ * 2) + koff[c], (char*)&Ks[1][0] + (wid * 2 + c) * 1024);
        async16(vgb + voff[c], (char*)&Vs[0][0] + (wid * 2 + c) * 1024);
    }
    __builtin_amdgcn_s_waitcnt(0x0F70);  // vmcnt(0) once, in prologue
    __syncthreads();

    const float C2 = 0.09016844f;        // log2(e)/16
    bf16x8 pfA, pfB;
    {
        union { uint32_t u[4]; bf16x8 v; } zz;
        zz.u[0] = 0; zz.u[1] = 0; zz.u[2] = 0; zz.u[3] = 0;
        pfA = zz.v; pfB = zz.v;
    }

    // rotating buffer pointers: kCur=K(t), kNxt=K(t+1), kDst<-K(t+2);
    // vP=V(t-1) (PV source), vQ=V(t), vR<-V(t+1)
    short* kCur = &Ks[0][0]; short* kNxt = &Ks[1][0]; short* kDst = &Ks[2][0];
    short* vP   = &Vs[2][0]; short* vQ   = &Vs[0][0]; short* vR   = &Vs[1][0];

    for (int t = 0; t < NITER; t++) {
        // stage K(t+2) -> kDst, V(t+1) -> vR (wrapped tiles are L2-hot dummies)
        {
            const char* kp = kgb + (size_t)((t + 2) & 15) * (KTILE * D_ * 2);
            const char* vp = vgb + (size_t)((t + 1) & 15) * (KTILE * 2);
#pragma unroll
            for (int c = 0; c < 2; c++) {
                async16(kp + koff[c], (char*)kDst + (wid * 2 + c) * 1024);
                async16(vp + voff[c], (char*)vR + (wid * 2 + c) * 1024);
            }
        }

        // ---- QK(t), swapped: S^T[k][q] = mfma(K, Q); two chains ----
        const char* kl = (const char*)kCur;
        floatx16 s0, s1;
#pragma unroll
        for (int r = 0; r < 16; r++) { s0[r] = 0.f; s1[r] = 0.f; }
        __builtin_amdgcn_s_setprio(1);
#pragma unroll
        for (int dt = 0; dt < 16; dt += 2) {
            bf16x8 kf0 = *(const bf16x8*)(kl + (KBb ^ (dt << 5)));
            bf16x8 kf1 = *(const bf16x8*)(kl + (KBb ^ ((dt + 1) << 5)));
            s0 = __builtin_amdgcn_mfma_f32_32x32x16_bf16(kf0, qf[dt], s0, 0, 0, 0);
            s1 = __builtin_amdgcn_mfma_f32_32x32x16_bf16(kf1, qf[dt + 1], s1, 0, 0, 0);
        }

        // ---- PV(t-1) from register P-fragments (unconditional) ----
        const char* vl = (const char*)vP;
#pragma unroll
        for (int n = 0; n < 8; n++) {
            bf16x8 vf0 = *(const bf16x8*)(vl + (VBb ^ (n << 11)));
            bf16x8 vf1 = *(const bf16x8*)(vl + (VBb ^ ((n << 11) | 32)));
            o[n] = __builtin_amdgcn_mfma_f32_32x32x16_bf16(pfA, vf0, o[n], 0, 0, 0);
            o[n] = __builtin_amdgcn_mfma_f32_32x32x16_bf16(pfB, vf1, o[n], 0, 0, 0);
        }
        __builtin_amdgcn_s_setprio(0);

        // ---- softmax(t): P = exp2(S*C2) masked, packed to bf16 A-frags ----
        uint32_t mb = (uint32_t)__ballot((mbits >> t) & 1) >> (hi * 4);
        uint32_t w[8];
#pragma unroll
        for (int i = 0; i < 8; i++) {
            const int r0 = 2 * i, r1 = 2 * i + 1;
            const int k0 = (r0 & 3) + 8 * (r0 >> 2);
            float sv0 = s0[r0] + s1[r0];
            float sv1 = s0[r1] + s1[r1];
            float e0 = ((mb >> k0) & 1) ? exp2f(sv0 * C2) : 0.f;
            float e1 = ((mb >> (k0 + 1)) & 1) ? exp2f(sv1 * C2) : 0.f;
            rsum += e0 + e1;
            w[i] = cvtpk_bf16(e0, e1);
        }
        pl32swap(w[0], w[2]); pl32swap(w[1], w[3]);
        pl32swap(w[4], w[6]); pl32swap(w[5], w[7]);
        {
            union { uint32_t u[4]; bf16x8 v; } ua, ub;
            ua.u[0] = w[0]; ua.u[1] = w[1]; ua.u[2] = w[2]; ua.u[3] = w[3];
            ub.u[0] = w[4]; ub.u[1] = w[5]; ub.u[2] = w[6]; ub.u[3] = w[7];
            pfA = ua.v; pfB = ub.v;
        }

        // counted drain: retire K(t+1),V(t); keep newest 4 in flight
        asm volatile("s_waitcnt vmcnt(4)" ::: "memory");
        __builtin_amdgcn_s_barrier();
        asm volatile("" ::: "memory");

        short* tk = kCur; kCur = kNxt; kNxt = kDst; kDst = tk;
        short* tv = vP;   vP = vQ;     vQ = vR;     vR = tv;
    }

    // ---- final PV(NITER-1): vP now holds V(15) ----
    {
        const char* vl = (const char*)vP;
        __builtin_amdgcn_s_setprio(1);
#pragma unroll
        for (int n = 0; n < 8; n++) {
            bf16x8 vf0 = *(const bf16x8*)(vl + (VBb ^ (n << 11)));
            bf16x8 vf1 = *(const bf16x8*)(vl + (VBb ^ ((n << 11) | 32)));
            o[n] = __builtin_amdgcn_mfma_f32_32x32x16_bf16(pfA, vf0, o[n], 0, 0, 0);
            o[n] = __builtin_amdgcn_mfma_f32_32x32x16_bf16(pfB, vf1, o[n], 0, 0, 0);
        }
        __builtin_amdgcn_s_setprio(0);
    }

    // rsum: lane holds half the k-sum for q=l31; add partner half (lane^32)
    rsum += __shfl_xor(rsum, 32);

    const size_t BLD = (size_t)B_ * L_ * D_;
    const size_t rowbase = (size_t)b * L_ + q0 + wid * 32;
    // O layout: lane holds O[q = (r&3)+8*(r>>2)+4*hi][d = n*32 + l31]
    if (z == 0) {
        float* po = Out + rowbase * D_;
#pragma unroll
        for (int n = 0; n < 8; n++)
#pragma unroll
            for (int r = 0; r < 16; r++) {
                int q = (r & 3) + 8 * (r >> 2) + 4 * hi;
                po[(size_t)q * D_ + n * 32 + l31] = o[n][r];
            }
    } else {
        // full-line chunked layout: chunk idx = ((((b*8+y)*8+w)*8+n)*2+h2)*64+lane
        _Float16* pp = Part + (size_t)(z - 1) * BLD;
#pragma unroll
        for (int n = 0; n < 8; n++)
#pragma unroll
            for (int h2 = 0; h2 < 2; h2++) {
                half8_t hv;
#pragma unroll
                for (int i = 0; i < 8; i++) hv[i] = (_Float16)o[n][h2 * 8 + i];
                size_t cidx = ((((size_t)((b * 8 + yb) * 8 + wid)) * 8 + n) * 2 + h2) * 64 + lane;
                *(half8_t*)(pp + cidx * 8) = hv;
            }
    }
    if (lane < 32) {
        Lpart[(size_t)z * (B_ * L_) + rowbase + lane] = rsum;
    }
}

// ---------------------------------------------------------------------------
// Normalize: out = (Out_f32 + sum of 3 Part_f16 slices) / (l0+l1+l2+l3).
// Part is in the chunked layout written by flash; gid == chunk index.
// One thread per 8-element chunk: grid = BLD/8/256 = 2048 blocks.
// ---------------------------------------------------------------------------
__global__ __launch_bounds__(256) void norm_kernel(
    float* __restrict__ Out, const _Float16* __restrict__ Part,
    const float* __restrict__ Lpart)
{
    const int gid  = blockIdx.x * 256 + threadIdx.x;   // 0 .. 524287
    const int lane = gid & 63;
    const int h2   = (gid >> 6) & 1;
    const int n    = (gid >> 7) & 7;
    const int w    = (gid >> 10) & 7;
    const int yb   = (gid >> 13) & 7;
    const int b    = gid >> 16;
    const int l31  = lane & 31, hi = lane >> 5;
    const int d    = n * 32 + l31;
    const int rowbase = b * L_ + yb * 256 + w * 32;
    const size_t BLD = (size_t)B_ * L_ * D_;
    const int BL = B_ * L_;

    float acc[8];
#pragma unroll
    for (int i = 0; i < 8; i++) acc[i] = 0.f;
#pragma unroll
    for (int zz = 0; zz < 3; zz++) {
        half8_t hv = *(const half8_t*)(Part + zz * BLD + (size_t)gid * 8);
#pragma unroll
        for (int i = 0; i < 8; i++) acc[i] += (float)hv[i];
    }
#pragma unroll
    for (int i = 0; i < 8; i++) {
        const int r = h2 * 8 + i;
        const int q = (r & 3) + 8 * (r >> 2) + 4 * hi;
        const int row = rowbase + q;
        float l = Lpart[row] + Lpart[BL + row] + Lpart[2 * BL + row] + Lpart[3 * BL + row];
        const size_t off = (size_t)row * D_ + d;
        Out[off] = (Out[off] + acc[i]) / l;
    }
}

extern "C" void kernel_launch(void* const* d_in, const int* in_sizes, int n_in,
                              void* d_out, int out_size, void* d_ws, size_t ws_size,
                              hipStream_t stream) {
    const float* query = (const float*)d_in[0];
    const float* key   = (const float*)d_in[1];
    const float* value = (const float*)d_in[2];
    const int*   mask  = (const int*)d_in[3];
    const float* Wq_w  = (const float*)d_in[4];
    const float* Wq_b  = (const float*)d_in[5];
    const float* Wk_w  = (const float*)d_in[6];
    const float* Wk_b  = (const float*)d_in[7];
    float* out = (float*)d_out;

    const size_t BLD = (size_t)B_ * L_ * D_;
    short* qb = (short*)d_ws;
    short* kb = qb + BLD;
    short* vt = kb + BLD;
    _Float16* part = (_Float16*)(vt + BLD);
    float* lpart = (float*)(part + 3 * BLD);

    prep_kernel<<<dim3(512), 256, 0, stream>>>(query, key, Wq_w, Wk_w, Wq_b, Wk_b,
                                               value, qb, kb, vt);
    flash_kernel<<<dim3(8, 8, 4), 512, 0, stream>>>(qb, kb, vt, mask, out, part, lpart);
    norm_kernel<<<dim3((B_ * L_ * D_ / 8) / 256), 256, 0, stream>>>(out, part, lpart);
}